// Round 11
// baseline (311.202 us; speedup 1.0000x reference)
//
#include <hip/hip_runtime.h>
#include <hip/hip_bf16.h>
#include <math.h>

#define F_IN 128
#define C1 16
#define C2 8

#define LBITS 8                 // 256 nodes per bucket
#define LOCAL (1 << LBITS)
#define NB_MAX 512              // supports N up to 131072
#define ITEMS 16                // edges per thread in phase A
#define EPB (256 * ITEMS)       // 4096 edges per phase-A block

static __device__ __forceinline__ unsigned short f2bf(float f) {
  __hip_bfloat16 h = __float2bfloat16(f);
  return *(unsigned short*)&h;
}

// ---------------- two-level bucket sort by dst ----------------
__global__ void bucket_hist(const int* __restrict__ dst, int* __restrict__ bcount, int E, int NB) {
  __shared__ int h[NB_MAX];
  for (int i = threadIdx.x; i < NB; i += blockDim.x) h[i] = 0;
  __syncthreads();
  int stride = gridDim.x * blockDim.x;
  int tid = blockIdx.x * blockDim.x + threadIdx.x;
  if ((E & 3) == 0) {
    const int4* d4 = (const int4*)dst;
    int n4 = E >> 2;
    for (int i = tid; i < n4; i += stride) {
      int4 d = d4[i];
      atomicAdd(&h[d.x >> LBITS], 1);
      atomicAdd(&h[d.y >> LBITS], 1);
      atomicAdd(&h[d.z >> LBITS], 1);
      atomicAdd(&h[d.w >> LBITS], 1);
    }
  } else {
    for (int e = tid; e < E; e += stride) atomicAdd(&h[dst[e] >> LBITS], 1);
  }
  __syncthreads();
  for (int i = threadIdx.x; i < NB; i += blockDim.x)
    if (h[i]) atomicAdd(&bcount[i], h[i]);
}

__global__ void bucket_scan(const int* __restrict__ bcount, int* __restrict__ bbase,
                            int* __restrict__ bcursor, int NB) {
  __shared__ int sd[NB_MAX];
  int t = threadIdx.x;
  int v = (t < NB) ? bcount[t] : 0;
  sd[t] = v;
  __syncthreads();
  int acc = v;
  for (int off = 1; off < NB_MAX; off <<= 1) {
    int u = (t >= off) ? sd[t - off] : 0;
    __syncthreads();
    acc += u;
    sd[t] = acc;
    __syncthreads();
  }
  if (t < NB) {
    int excl = acc - v;
    bbase[t] = excl;
    bcursor[t] = excl;
    if (t == NB - 1) bbase[NB] = acc;
  }
}

// Phase A: block-local counting sort into LDS stage, then coalesced sweep to global.
__global__ __launch_bounds__(256) void phaseA_lds(const int* __restrict__ src,
                                                  const int* __restrict__ dst,
                                                  int* __restrict__ bcursor,
                                                  int* __restrict__ packed, int E, int NB) {
  __shared__ int hist[NB_MAX];    // counts -> local cursor
  __shared__ int lbase[NB_MAX];   // local exclusive prefix
  __shared__ int gbase[NB_MAX];   // reserved global chunk base
  __shared__ int sdata[256];
  __shared__ int stage[EPB];
  __shared__ unsigned short stageb[EPB];
  int t = threadIdx.x;
  for (int i = t; i < NB; i += 256) hist[i] = 0;
  __syncthreads();
  int base = blockIdx.x * EPB;
  int vals[ITEMS];
  int bkt[ITEMS];
  bool vec = ((E & 3) == 0) && (base + EPB <= E);
  if (vec) {
    const int4* s4 = (const int4*)(src + base);
    const int4* d4 = (const int4*)(dst + base);
#pragma unroll
    for (int q = 0; q < ITEMS / 4; q++) {
      int idx = q * 256 + t;
      int4 sv = s4[idx];
      int4 dv = d4[idx];
      int ss[4] = {sv.x, sv.y, sv.z, sv.w};
      int dd[4] = {dv.x, dv.y, dv.z, dv.w};
#pragma unroll
      for (int r = 0; r < 4; r++) {
        int k = q * 4 + r;
        bkt[k] = dd[r] >> LBITS;
        vals[k] = (ss[r] << LBITS) | (dd[r] & (LOCAL - 1));
        atomicAdd(&hist[bkt[k]], 1);
      }
    }
  } else {
#pragma unroll
    for (int k = 0; k < ITEMS; k++) {
      int e = base + k * 256 + t;
      if (e < E) {
        int s = src[e];
        int d = dst[e];
        bkt[k] = d >> LBITS;
        vals[k] = (s << LBITS) | (d & (LOCAL - 1));
        atomicAdd(&hist[bkt[k]], 1);
      } else {
        bkt[k] = -1;
      }
    }
  }
  __syncthreads();
  // block-wide exclusive scan over hist[0..NB): 2 entries/thread
  int i0 = 2 * t, i1 = 2 * t + 1;
  int h0 = (i0 < NB) ? hist[i0] : 0;
  int h1 = (i1 < NB) ? hist[i1] : 0;
  int s2 = h0 + h1;
  sdata[t] = s2;
  __syncthreads();
  int acc = s2;
  for (int off = 1; off < 256; off <<= 1) {
    int u = (t >= off) ? sdata[t - off] : 0;
    __syncthreads();
    acc += u;
    sdata[t] = acc;
    __syncthreads();
  }
  int excl = acc - s2;
  if (i0 < NB) lbase[i0] = excl;
  if (i1 < NB) lbase[i1] = excl + h0;
  __syncthreads();
  for (int i = t; i < NB; i += 256) {
    int c = hist[i];
    gbase[i] = c ? atomicAdd(&bcursor[i], c) : 0;
    hist[i] = lbase[i];
  }
  __syncthreads();
  if (vec) {
#pragma unroll
    for (int k = 0; k < ITEMS; k++) {
      int lp = atomicAdd(&hist[bkt[k]], 1);
      stage[lp] = vals[k];
      stageb[lp] = (unsigned short)bkt[k];
    }
  } else {
#pragma unroll
    for (int k = 0; k < ITEMS; k++) {
      if (bkt[k] >= 0) {
        int lp = atomicAdd(&hist[bkt[k]], 1);
        stage[lp] = vals[k];
        stageb[lp] = (unsigned short)bkt[k];
      }
    }
  }
  __syncthreads();
  int blockE = E - base;
  if (blockE > EPB) blockE = EPB;
  for (int i = t; i < blockE; i += 256) {
    int b = stageb[i];
    packed[gbase[b] + (i - lbase[b])] = stage[i];
  }
}

// Phase B: per-bucket counting sort; ssrc packs (src<<5)|(node&31) so the GAT
// kernels recover the owning node without a search.
__global__ void phaseB_sort(const int* __restrict__ packed, const int* __restrict__ bbase,
                            int* __restrict__ row_ptr, int* __restrict__ ssrc, int N, int E) {
  __shared__ int h[LOCAL];
  __shared__ int sd[LOCAL];
  int b = blockIdx.x;
  int t = threadIdx.x;  // blockDim.x == LOCAL == 256
  int beg = bbase[b], end = bbase[b + 1];
  int node0 = b << LBITS;
  h[t] = 0;
  __syncthreads();
  for (int j = beg + t; j < end; j += blockDim.x) atomicAdd(&h[packed[j] & (LOCAL - 1)], 1);
  __syncthreads();
  int cnt = h[t];
  sd[t] = cnt;
  __syncthreads();
  int acc = cnt;
  for (int off = 1; off < LOCAL; off <<= 1) {
    int u = (t >= off) ? sd[t - off] : 0;
    __syncthreads();
    acc += u;
    sd[t] = acc;
    __syncthreads();
  }
  int myex = acc - cnt;
  int node = node0 + t;
  if (node < N) row_ptr[node] = beg + myex;
  h[t] = beg + myex;
  if (b == gridDim.x - 1 && t == 0) row_ptr[N] = E;
  __syncthreads();
  for (int j = beg + t; j < end; j += blockDim.x) {
    int v = packed[j];
    int l = v & (LOCAL - 1);
    int p = atomicAdd(&h[l], 1);
    ssrc[p] = ((v >> LBITS) << 5) | (l & 31);
  }
}

// ---------------- dense transforms: matrix-split (blockIdx.x % 3) ----------------
__global__ __launch_bounds__(256) void gemm3_128x16(
    const float* __restrict__ x, const float* __restrict__ Wl, const float* __restrict__ Wr,
    const float* __restrict__ Wlin, const float* __restrict__ blin,
    __hip_bfloat16* __restrict__ XLh, float* __restrict__ XR, float* __restrict__ SK, int N) {
  int bx = blockIdx.x;
  int mat = bx % 3;
  int node = (bx / 3) * 256 + threadIdx.x;
  if (node >= N) return;
  const float* __restrict__ W = (mat == 0) ? Wl : (mat == 1) ? Wr : Wlin;
  const float4* xr4 = (const float4*)(x + (size_t)node * F_IN);
  float acc[16];
#pragma unroll
  for (int c = 0; c < 16; c++) acc[c] = 0.f;
#pragma unroll 8
  for (int kk = 0; kk < F_IN / 4; kk++) {
    float4 xv = xr4[kk];
    float xs[4] = {xv.x, xv.y, xv.z, xv.w};
#pragma unroll
    for (int j = 0; j < 4; j++) {
      int k = kk * 4 + j;
#pragma unroll
      for (int c = 0; c < 16; c++) acc[c] = fmaf(xs[j], W[k * 16 + c], acc[c]);
    }
  }
  if (mat == 0) {
    unsigned int pk[8];
#pragma unroll
    for (int i = 0; i < 8; i++)
      pk[i] = (unsigned)f2bf(acc[2 * i]) | ((unsigned)f2bf(acc[2 * i + 1]) << 16);
    uint4* xlp = (uint4*)(XLh + (size_t)node * 16);
    xlp[0] = make_uint4(pk[0], pk[1], pk[2], pk[3]);
    xlp[1] = make_uint4(pk[4], pk[5], pk[6], pk[7]);
  } else if (mat == 1) {
    float4* xrp = (float4*)(XR + (size_t)node * 16);
#pragma unroll
    for (int q = 0; q < 4; q++)
      xrp[q] = make_float4(acc[4 * q], acc[4 * q + 1], acc[4 * q + 2], acc[4 * q + 3]);
  } else {
    float4* skp = (float4*)(SK + (size_t)node * 16);
#pragma unroll
    for (int q = 0; q < 4; q++)
      skp[q] = make_float4(acc[4 * q] + blin[4 * q], acc[4 * q + 1] + blin[4 * q + 1],
                           acc[4 * q + 2] + blin[4 * q + 2], acc[4 * q + 3] + blin[4 * q + 3]);
  }
}

// ---------------- GAT layer: node-id in ssrc, pre-scaled ppool ----------------
// Phase S: edge-per-lane; node id decoded from ssrc (no search). p=exp(score)->ppool.
// Phase D: per-node S0 (one shuffle-reduce); then ppool *= invS0*t (group-local).
// Phase 2: q = v*ps; w=exp(q); S1+=w; S2+=w*q; result = S2/(S1*t).
template <int C, int POOL, bool HEAD, bool FUSEG2>
__global__ __launch_bounds__(256) void gat_layer(
    const __hip_bfloat16* __restrict__ XLh, const float* __restrict__ XR,
    const float* __restrict__ SK, const float* __restrict__ att, const float* __restrict__ bias,
    const float* __restrict__ tp, const int* __restrict__ row_ptr, const int* __restrict__ ssrc,
    float* __restrict__ H, int N,
    const float* __restrict__ P0, const float* __restrict__ P1, const float* __restrict__ P2,
    const float* __restrict__ P3, const float* __restrict__ P4, const float* __restrict__ P5,
    const float* __restrict__ P6, const float* __restrict__ P7,
    __hip_bfloat16* __restrict__ XL2h, float* __restrict__ XR2, float* __restrict__ SK2,
    float* __restrict__ out) {
  constexpr int NPB = 256 / C;
  __shared__ __align__(16) unsigned short vpool[POOL * C];
  __shared__ float ppool[POOL];
  __shared__ __align__(16) float xrl[NPB * C];
  __shared__ int nb[NPB + 1];
  __shared__ float hsh[(HEAD || FUSEG2) ? NPB * C : 1];
  __shared__ float wfuse[FUSEG2 ? 392 : 1];
  int t = threadIdx.x;
  int node0 = blockIdx.x * NPB;

  if (t <= NPB) {
    int nd = node0 + t;
    nb[t] = row_ptr[(nd < N) ? nd : N];
  }
  {
    size_t xi = (size_t)node0 * C + t;
    xrl[t] = (xi < (size_t)N * C) ? XR[xi] : 0.f;
  }
  if constexpr (FUSEG2) {
    for (int i = t; i < 392; i += 256)
      wfuse[i] = (i < 128) ? P0[i] : (i < 256) ? P1[i - 128] : (i < 384) ? P2[i - 256] : P3[i - 384];
  }
  float attr[C];
#pragma unroll
  for (int cc = 0; cc < C; cc++) attr[cc] = att[cc];
  float tval = tp[0];
  __syncthreads();

  int bbeg = nb[0];
  int nE = nb[NPB] - bbeg;
  int nCap = (nE < POOL) ? nE : POOL;
  const unsigned short* XLu = (const unsigned short*)XLh;

  // ---- Phase S ----
  for (int slot = t; slot < nCap; slot += 256) {
    int sp = ssrc[bbeg + slot];
    int s = sp >> 5;
    int g = sp & (NPB - 1);
    float v[C];
    if constexpr (C == 16) {
      const uint4* gp = (const uint4*)(XLu + (size_t)s * 16);
      uint4 a = gp[0], b = gp[1];
      *(uint4*)&vpool[slot * 16] = a;
      *(uint4*)&vpool[slot * 16 + 8] = b;
      unsigned arr[8] = {a.x, a.y, a.z, a.w, b.x, b.y, b.z, b.w};
#pragma unroll
      for (int i = 0; i < 8; i++) {
        v[2 * i] = __uint_as_float(arr[i] << 16);
        v[2 * i + 1] = __uint_as_float(arr[i] & 0xffff0000u);
      }
    } else {
      const uint4* gp = (const uint4*)(XLu + (size_t)s * 8);
      uint4 a = gp[0];
      *(uint4*)&vpool[slot * 8] = a;
      unsigned arr[4] = {a.x, a.y, a.z, a.w};
#pragma unroll
      for (int i = 0; i < 4; i++) {
        v[2 * i] = __uint_as_float(arr[i] << 16);
        v[2 * i + 1] = __uint_as_float(arr[i] & 0xffff0000u);
      }
    }
    float xr[C];
    const float4* xp = (const float4*)&xrl[g * C];
#pragma unroll
    for (int q = 0; q < C / 4; q++) {
      float4 f = xp[q];
      xr[4 * q] = f.x;
      xr[4 * q + 1] = f.y;
      xr[4 * q + 2] = f.z;
      xr[4 * q + 3] = f.w;
    }
    float p0 = 0.f, p1 = 0.f, p2 = 0.f, p3 = 0.f;
#pragma unroll
    for (int cc = 0; cc < C; cc += 4) {
      float u0 = v[cc] + xr[cc];
      float u1 = v[cc + 1] + xr[cc + 1];
      float u2 = v[cc + 2] + xr[cc + 2];
      float u3 = v[cc + 3] + xr[cc + 3];
      p0 = fmaf(fmaxf(u0, 0.2f * u0), attr[cc], p0);
      p1 = fmaf(fmaxf(u1, 0.2f * u1), attr[cc + 1], p1);
      p2 = fmaf(fmaxf(u2, 0.2f * u2), attr[cc + 2], p2);
      p3 = fmaf(fmaxf(u3, 0.2f * u3), attr[cc + 3], p3);
    }
    ppool[slot] = __expf((p0 + p1) + (p2 + p3));
  }
  __syncthreads();

  int g = t / C;
  int c = t % C;
  int base = nb[g] - bbeg;
  int deg = nb[g + 1] - nb[g];
  int capd = POOL - base;
  capd = capd < 0 ? 0 : (capd > deg ? deg : capd);

  // ---- Phase D: S0 per node, then pre-scale ppool by invS0*t (group-local) ----
  float invS0;
  {
    float s0 = 0.f;
    for (int j = c; j < capd; j += C) s0 += ppool[base + j];
    for (int j = capd + c; j < deg; j += C) {  // overflow fallback (~never)
      int s = ssrc[bbeg + base + j] >> 5;
      float sc = 0.f;
#pragma unroll
      for (int cc = 0; cc < C; cc++) {
        float v = __bfloat162float(XLh[(size_t)s * C + cc]);
        float u = v + xrl[g * C + cc];
        sc = fmaf(fmaxf(u, 0.2f * u), attr[cc], sc);
      }
      s0 += __expf(sc);
    }
#pragma unroll
    for (int m = 1; m < C; m <<= 1) s0 += __shfl_xor(s0, m, C);
    invS0 = (deg > 0) ? 1.0f / s0 : 0.f;
    float a = invS0 * tval;
    for (int j = c; j < capd; j += C) ppool[base + j] *= a;
  }
  // no barrier: each group touches only its own slots, within one wave

  // ---- Phase 2: q = v*ps; w = exp(q); S1 += w; S2 += w*q ----
  float S1 = 0.f, S2 = 0.f, S1b = 0.f, S2b = 0.f;
  int jj = 0;
  for (; jj + 2 <= capd; jj += 2) {
    int sl0 = base + jj;
    float v0 = __uint_as_float(((unsigned)vpool[sl0 * C + c]) << 16);
    float q0 = v0 * ppool[sl0];
    float v1 = __uint_as_float(((unsigned)vpool[(sl0 + 1) * C + c]) << 16);
    float q1 = v1 * ppool[sl0 + 1];
    float w0 = __expf(q0);
    float w1 = __expf(q1);
    S1 += w0;
    S2 = fmaf(w0, q0, S2);
    S1b += w1;
    S2b = fmaf(w1, q1, S2b);
  }
  for (; jj < capd; jj++) {
    int sl = base + jj;
    float v = __uint_as_float(((unsigned)vpool[sl * C + c]) << 16);
    float q = v * ppool[sl];
    float w = __expf(q);
    S1 += w;
    S2 = fmaf(w, q, S2);
  }
  for (; jj < deg; jj++) {  // overflow fallback (~never)
    int s = ssrc[bbeg + base + jj] >> 5;
    float sc = 0.f, vc = 0.f;
#pragma unroll
    for (int cc = 0; cc < C; cc++) {
      float v = __bfloat162float(XLh[(size_t)s * C + cc]);
      if (cc == c) vc = v;
      float u = v + xrl[g * C + cc];
      sc = fmaf(fmaxf(u, 0.2f * u), attr[cc], sc);
    }
    float p = __expf(sc);
    float q = vc * (p * invS0 * tval);
    float w = __expf(q);
    S1 += w;
    S2 = fmaf(w, q, S2);
  }
  S1 += S1b;
  S2 += S2b;

  int node = node0 + g;
  bool valid = node < N;
  float hval = 0.f;
  if (valid) {
    float td = (tval != 0.f) ? tval : 1.f;  // t==0 never occurs in harness inputs
    float gat = (deg > 0) ? (S2 / (S1 * td)) : 0.f;
    hval = fmaxf(gat + bias[c] + SK[(size_t)node * C + c], 0.f);
  }
  if constexpr (FUSEG2) {
    hsh[g * C + c] = hval;
    __syncthreads();
    if (t < NPB * 8) {  // 16 nodes x 8 out-channels
      int g2 = t >> 3, c2 = t & 7;
      int nd = node0 + g2;
      if (nd < N) {
        float a0 = 0.f, a1 = 0.f, a2 = 0.f;
#pragma unroll
        for (int k = 0; k < 16; k++) {
          float hv = hsh[g2 * 16 + k];
          a0 = fmaf(hv, wfuse[k * 8 + c2], a0);
          a1 = fmaf(hv, wfuse[128 + k * 8 + c2], a1);
          a2 = fmaf(hv, wfuse[256 + k * 8 + c2], a2);
        }
        ((unsigned short*)XL2h)[(size_t)nd * 8 + c2] = f2bf(a0);
        XR2[(size_t)nd * 8 + c2] = a1;
        SK2[(size_t)nd * 8 + c2] = a2 + wfuse[384 + c2];
      }
    }
  } else if constexpr (HEAD) {
    hsh[g * C + c] = hval;
    __syncthreads();
    if (t < NPB) {
      int nd = node0 + t;
      if (nd < N) {
        float h[8];
#pragma unroll
        for (int k = 0; k < 8; k++) h[k] = hsh[t * 8 + k];
        float s4 = 0.f;
#pragma unroll
        for (int cc = 0; cc < 8; cc++) {
          float z = P1[cc];  // b3
#pragma unroll
          for (int k = 0; k < 8; k++) z = fmaf(h[k], P0[k * 8 + cc], z);  // W3
          z = fmaxf(z, 0.f);
          s4 = fmaf(z, P2[cc], s4);  // W4
        }
        s4 = fmaxf(s4 + P3[0], 0.f);                    // b4
        float s5 = fmaxf(fmaf(s4, P4[0], P5[0]), 0.f);  // W5,b5
        float zo = fmaf(s5, P6[0], P7[0]);              // Wout,bout
        float ls;
        if (zo >= 0.f)
          ls = -log1pf(expf(-zo));
        else
          ls = zo - log1pf(expf(zo));
        out[nd] = ls;
      }
    }
  } else {
    if (valid) H[(size_t)node * C + c] = hval;
  }
}

extern "C" void kernel_launch(void* const* d_in, const int* in_sizes, int n_in,
                              void* d_out, int out_size, void* d_ws, size_t ws_size,
                              hipStream_t stream) {
  const float* x = (const float*)d_in[0];
  const int* ei = (const int*)d_in[1];
  const float* Wl1 = (const float*)d_in[3];
  const float* Wr1 = (const float*)d_in[4];
  const float* att1 = (const float*)d_in[5];
  const float* b1 = (const float*)d_in[6];
  const float* Wlin1 = (const float*)d_in[7];
  const float* blin1 = (const float*)d_in[8];
  const float* Wl2 = (const float*)d_in[9];
  const float* Wr2 = (const float*)d_in[10];
  const float* att2 = (const float*)d_in[11];
  const float* b2 = (const float*)d_in[12];
  const float* Wlin2 = (const float*)d_in[13];
  const float* blin2 = (const float*)d_in[14];
  const float* t = (const float*)d_in[15];
  const float* W3 = (const float*)d_in[16];
  const float* b3 = (const float*)d_in[17];
  const float* W4 = (const float*)d_in[18];
  const float* b4 = (const float*)d_in[19];
  const float* W5 = (const float*)d_in[20];
  const float* b5 = (const float*)d_in[21];
  const float* Wout = (const float*)d_in[22];
  const float* bout = (const float*)d_in[23];
  float* out = (float*)d_out;

  int N = in_sizes[0] / F_IN;
  int E = in_sizes[1] / 2;
  const int* src = ei;
  const int* dst = ei + E;
  int NB = (N + LOCAL - 1) >> LBITS;  // 391 for N=100000

  char* ws = (char*)d_ws;
  size_t off = 0;
  auto alloc = [&](size_t bytes) -> void* {
    void* p = ws + off;
    off = (off + bytes + 255) & ~(size_t)255;
    return p;
  };
  int* bcount = (int*)alloc((size_t)NB * 4);
  int* bbase = (int*)alloc((size_t)(NB + 1) * 4);
  int* bcursor = (int*)alloc((size_t)NB * 4);
  int* packed = (int*)alloc((size_t)E * 4);
  int* row_ptr = (int*)alloc((size_t)(N + 1) * 4);
  int* ssrc = (int*)alloc((size_t)E * 4);
  __hip_bfloat16* XL1 = (__hip_bfloat16*)alloc((size_t)N * C1 * 2);
  float* XR1 = (float*)alloc((size_t)N * C1 * 4);
  float* SK1 = (float*)alloc((size_t)N * C1 * 4);
  __hip_bfloat16* XL2 = (__hip_bfloat16*)alloc((size_t)N * C2 * 2);
  float* XR2 = (float*)alloc((size_t)N * C2 * 4);
  float* SK2 = (float*)alloc((size_t)N * C2 * 4);

  int nblkA = (E + EPB - 1) / EPB;
  int nodeBlk = (N + 255) / 256;  // 391

  hipMemsetAsync(bcount, 0, (size_t)NB * 4, stream);
  hipLaunchKernelGGL(bucket_hist, dim3(1024), dim3(256), 0, stream, dst, bcount, E, NB);
  hipLaunchKernelGGL(bucket_scan, dim3(1), dim3(NB_MAX), 0, stream, bcount, bbase, bcursor, NB);
  hipLaunchKernelGGL(phaseA_lds, dim3(nblkA), dim3(256), 0, stream, src, dst, bcursor, packed, E,
                     NB);
  hipLaunchKernelGGL(phaseB_sort, dim3(NB), dim3(LOCAL), 0, stream, packed, bbase, row_ptr, ssrc, N,
                     E);
  hipLaunchKernelGGL(gemm3_128x16, dim3(nodeBlk * 3), dim3(256), 0, stream, x, Wl1, Wr1,
                     Wlin1, blin1, XL1, XR1, SK1, N);
  hipLaunchKernelGGL((gat_layer<16, 640, false, true>), dim3((N + 15) / 16), dim3(256), 0, stream,
                     XL1, XR1, SK1, att1, b1, t, row_ptr, ssrc, nullptr, N, Wl2, Wr2, Wlin2, blin2,
                     nullptr, nullptr, nullptr, nullptr, XL2, XR2, SK2, nullptr);
  hipLaunchKernelGGL((gat_layer<8, 1216, true, false>), dim3((N + 31) / 32), dim3(256), 0, stream,
                     XL2, XR2, SK2, att2, b2, t, row_ptr, ssrc, nullptr, N, W3, b3, W4, b4, W5, b5,
                     Wout, bout, nullptr, nullptr, nullptr, out);
}

// Round 12
// 302.700 us; speedup vs baseline: 1.0281x; 1.0281x over previous
//
#include <hip/hip_runtime.h>
#include <hip/hip_bf16.h>
#include <math.h>

#define F_IN 128
#define C1 16
#define C2 8

#define LBITS 8                 // 256 nodes per bucket
#define LOCAL (1 << LBITS)
#define NB_MAX 512              // supports N up to 131072
#define ITEMS 16                // edges per thread in phase A
#define EPB (256 * ITEMS)       // 4096 edges per phase-A block
#define HISTBLK 512             // blocks of the fused kernel doing histogram

static __device__ __forceinline__ unsigned short f2bf(float f) {
  __hip_bfloat16 h = __float2bfloat16(f);
  return *(unsigned short*)&h;
}

// ---------------- fused: bucket histogram + layer-1 dense transforms ----------------
// Blocks [0, HISTBLK) histogram dst>>LBITS; blocks [HISTBLK, ...) run the
// matrix-split gemm (independent work — co-scheduling overlaps their stalls).
__global__ __launch_bounds__(256) void hist_gemm(
    const int* __restrict__ dst, int* __restrict__ bcount, int E, int NB,
    const float* __restrict__ x, const float* __restrict__ Wl, const float* __restrict__ Wr,
    const float* __restrict__ Wlin, const float* __restrict__ blin,
    __hip_bfloat16* __restrict__ XLh, float* __restrict__ XR, float* __restrict__ SK, int N) {
  if (blockIdx.x < HISTBLK) {
    __shared__ int h[NB_MAX];
    for (int i = threadIdx.x; i < NB; i += blockDim.x) h[i] = 0;
    __syncthreads();
    int stride = HISTBLK * 256;
    int tid = blockIdx.x * 256 + threadIdx.x;
    if ((E & 3) == 0) {
      const int4* d4 = (const int4*)dst;
      int n4 = E >> 2;
      for (int i = tid; i < n4; i += stride) {
        int4 d = d4[i];
        atomicAdd(&h[d.x >> LBITS], 1);
        atomicAdd(&h[d.y >> LBITS], 1);
        atomicAdd(&h[d.z >> LBITS], 1);
        atomicAdd(&h[d.w >> LBITS], 1);
      }
    } else {
      for (int e = tid; e < E; e += stride) atomicAdd(&h[dst[e] >> LBITS], 1);
    }
    __syncthreads();
    for (int i = threadIdx.x; i < NB; i += blockDim.x)
      if (h[i]) atomicAdd(&bcount[i], h[i]);
  } else {
    int bx = blockIdx.x - HISTBLK;
    int mat = bx % 3;
    int node = (bx / 3) * 256 + threadIdx.x;
    if (node >= N) return;
    const float* __restrict__ W = (mat == 0) ? Wl : (mat == 1) ? Wr : Wlin;
    const float4* xr4 = (const float4*)(x + (size_t)node * F_IN);
    float acc[16];
#pragma unroll
    for (int c = 0; c < 16; c++) acc[c] = 0.f;
#pragma unroll 8
    for (int kk = 0; kk < F_IN / 4; kk++) {
      float4 xv = xr4[kk];
      float xs[4] = {xv.x, xv.y, xv.z, xv.w};
#pragma unroll
      for (int j = 0; j < 4; j++) {
        int k = kk * 4 + j;
#pragma unroll
        for (int c = 0; c < 16; c++) acc[c] = fmaf(xs[j], W[k * 16 + c], acc[c]);
      }
    }
    if (mat == 0) {
      unsigned int pk[8];
#pragma unroll
      for (int i = 0; i < 8; i++)
        pk[i] = (unsigned)f2bf(acc[2 * i]) | ((unsigned)f2bf(acc[2 * i + 1]) << 16);
      uint4* xlp = (uint4*)(XLh + (size_t)node * 16);
      xlp[0] = make_uint4(pk[0], pk[1], pk[2], pk[3]);
      xlp[1] = make_uint4(pk[4], pk[5], pk[6], pk[7]);
    } else if (mat == 1) {
      float4* xrp = (float4*)(XR + (size_t)node * 16);
#pragma unroll
      for (int q = 0; q < 4; q++)
        xrp[q] = make_float4(acc[4 * q], acc[4 * q + 1], acc[4 * q + 2], acc[4 * q + 3]);
    } else {
      float4* skp = (float4*)(SK + (size_t)node * 16);
#pragma unroll
      for (int q = 0; q < 4; q++)
        skp[q] = make_float4(acc[4 * q] + blin[4 * q], acc[4 * q + 1] + blin[4 * q + 1],
                             acc[4 * q + 2] + blin[4 * q + 2], acc[4 * q + 3] + blin[4 * q + 3]);
    }
  }
}

__global__ void bucket_scan(const int* __restrict__ bcount, int* __restrict__ bbase,
                            int* __restrict__ bcursor, int NB) {
  __shared__ int sd[NB_MAX];
  int t = threadIdx.x;
  int v = (t < NB) ? bcount[t] : 0;
  sd[t] = v;
  __syncthreads();
  int acc = v;
  for (int off = 1; off < NB_MAX; off <<= 1) {
    int u = (t >= off) ? sd[t - off] : 0;
    __syncthreads();
    acc += u;
    sd[t] = acc;
    __syncthreads();
  }
  if (t < NB) {
    int excl = acc - v;
    bbase[t] = excl;
    bcursor[t] = excl;
    if (t == NB - 1) bbase[NB] = acc;
  }
}

// Phase A: block-local counting sort into LDS stage, then coalesced sweep to global.
__global__ __launch_bounds__(256) void phaseA_lds(const int* __restrict__ src,
                                                  const int* __restrict__ dst,
                                                  int* __restrict__ bcursor,
                                                  int* __restrict__ packed, int E, int NB) {
  __shared__ int hist[NB_MAX];
  __shared__ int lbase[NB_MAX];
  __shared__ int gbase[NB_MAX];
  __shared__ int sdata[256];
  __shared__ int stage[EPB];
  __shared__ unsigned short stageb[EPB];
  int t = threadIdx.x;
  for (int i = t; i < NB; i += 256) hist[i] = 0;
  __syncthreads();
  int base = blockIdx.x * EPB;
  int vals[ITEMS];
  int bkt[ITEMS];
  bool vec = ((E & 3) == 0) && (base + EPB <= E);
  if (vec) {
    const int4* s4 = (const int4*)(src + base);
    const int4* d4 = (const int4*)(dst + base);
#pragma unroll
    for (int q = 0; q < ITEMS / 4; q++) {
      int idx = q * 256 + t;
      int4 sv = s4[idx];
      int4 dv = d4[idx];
      int ss[4] = {sv.x, sv.y, sv.z, sv.w};
      int dd[4] = {dv.x, dv.y, dv.z, dv.w};
#pragma unroll
      for (int r = 0; r < 4; r++) {
        int k = q * 4 + r;
        bkt[k] = dd[r] >> LBITS;
        vals[k] = (ss[r] << LBITS) | (dd[r] & (LOCAL - 1));
        atomicAdd(&hist[bkt[k]], 1);
      }
    }
  } else {
#pragma unroll
    for (int k = 0; k < ITEMS; k++) {
      int e = base + k * 256 + t;
      if (e < E) {
        int s = src[e];
        int d = dst[e];
        bkt[k] = d >> LBITS;
        vals[k] = (s << LBITS) | (d & (LOCAL - 1));
        atomicAdd(&hist[bkt[k]], 1);
      } else {
        bkt[k] = -1;
      }
    }
  }
  __syncthreads();
  int i0 = 2 * t, i1 = 2 * t + 1;
  int h0 = (i0 < NB) ? hist[i0] : 0;
  int h1 = (i1 < NB) ? hist[i1] : 0;
  int s2 = h0 + h1;
  sdata[t] = s2;
  __syncthreads();
  int acc = s2;
  for (int off = 1; off < 256; off <<= 1) {
    int u = (t >= off) ? sdata[t - off] : 0;
    __syncthreads();
    acc += u;
    sdata[t] = acc;
    __syncthreads();
  }
  int excl = acc - s2;
  if (i0 < NB) lbase[i0] = excl;
  if (i1 < NB) lbase[i1] = excl + h0;
  __syncthreads();
  for (int i = t; i < NB; i += 256) {
    int c = hist[i];
    gbase[i] = c ? atomicAdd(&bcursor[i], c) : 0;
    hist[i] = lbase[i];
  }
  __syncthreads();
  if (vec) {
#pragma unroll
    for (int k = 0; k < ITEMS; k++) {
      int lp = atomicAdd(&hist[bkt[k]], 1);
      stage[lp] = vals[k];
      stageb[lp] = (unsigned short)bkt[k];
    }
  } else {
#pragma unroll
    for (int k = 0; k < ITEMS; k++) {
      if (bkt[k] >= 0) {
        int lp = atomicAdd(&hist[bkt[k]], 1);
        stage[lp] = vals[k];
        stageb[lp] = (unsigned short)bkt[k];
      }
    }
  }
  __syncthreads();
  int blockE = E - base;
  if (blockE > EPB) blockE = EPB;
  for (int i = t; i < blockE; i += 256) {
    int b = stageb[i];
    packed[gbase[b] + (i - lbase[b])] = stage[i];
  }
}

// Phase B: per-bucket counting sort; ssrc packs (src<<5)|(node&31).
__global__ void phaseB_sort(const int* __restrict__ packed, const int* __restrict__ bbase,
                            int* __restrict__ row_ptr, int* __restrict__ ssrc, int N, int E) {
  __shared__ int h[LOCAL];
  __shared__ int sd[LOCAL];
  int b = blockIdx.x;
  int t = threadIdx.x;
  int beg = bbase[b], end = bbase[b + 1];
  int node0 = b << LBITS;
  h[t] = 0;
  __syncthreads();
  for (int j = beg + t; j < end; j += blockDim.x) atomicAdd(&h[packed[j] & (LOCAL - 1)], 1);
  __syncthreads();
  int cnt = h[t];
  sd[t] = cnt;
  __syncthreads();
  int acc = cnt;
  for (int off = 1; off < LOCAL; off <<= 1) {
    int u = (t >= off) ? sd[t - off] : 0;
    __syncthreads();
    acc += u;
    sd[t] = acc;
    __syncthreads();
  }
  int myex = acc - cnt;
  int node = node0 + t;
  if (node < N) row_ptr[node] = beg + myex;
  h[t] = beg + myex;
  if (b == gridDim.x - 1 && t == 0) row_ptr[N] = E;
  __syncthreads();
  for (int j = beg + t; j < end; j += blockDim.x) {
    int v = packed[j];
    int l = v & (LOCAL - 1);
    int p = atomicAdd(&h[l], 1);
    ssrc[p] = ((v >> LBITS) << 5) | (l & 31);
  }
}

// ---------------- GAT layer ----------------
// hsh aliases vpool (dead after phase 2; barrier-protected) to save LDS -> 7 blocks/CU.
template <int C, int POOL, bool HEAD, bool FUSEG2>
__global__ __launch_bounds__(256) void gat_layer(
    const __hip_bfloat16* __restrict__ XLh, const float* __restrict__ XR,
    const float* __restrict__ SK, const float* __restrict__ att, const float* __restrict__ bias,
    const float* __restrict__ tp, const int* __restrict__ row_ptr, const int* __restrict__ ssrc,
    float* __restrict__ H, int N,
    const float* __restrict__ P0, const float* __restrict__ P1, const float* __restrict__ P2,
    const float* __restrict__ P3, const float* __restrict__ P4, const float* __restrict__ P5,
    const float* __restrict__ P6, const float* __restrict__ P7,
    __hip_bfloat16* __restrict__ XL2h, float* __restrict__ XR2, float* __restrict__ SK2,
    float* __restrict__ out) {
  constexpr int NPB = 256 / C;
  __shared__ __align__(16) unsigned short vpool[POOL * C];
  __shared__ float ppool[POOL];
  __shared__ __align__(16) float xrl[NPB * C];
  __shared__ int nb[NPB + 1];
  __shared__ float wfuse[FUSEG2 ? 392 : 1];
  float* hsh = (float*)vpool;  // aliased: used only after phase 2 (barrier-protected)
  int t = threadIdx.x;
  int node0 = blockIdx.x * NPB;

  if (t <= NPB) {
    int nd = node0 + t;
    nb[t] = row_ptr[(nd < N) ? nd : N];
  }
  {
    size_t xi = (size_t)node0 * C + t;
    xrl[t] = (xi < (size_t)N * C) ? XR[xi] : 0.f;
  }
  if constexpr (FUSEG2) {
    for (int i = t; i < 392; i += 256)
      wfuse[i] = (i < 128) ? P0[i] : (i < 256) ? P1[i - 128] : (i < 384) ? P2[i - 256] : P3[i - 384];
  }
  float attr[C];
#pragma unroll
  for (int cc = 0; cc < C; cc++) attr[cc] = att[cc];
  float tval = tp[0];
  __syncthreads();

  int bbeg = nb[0];
  int nE = nb[NPB] - bbeg;
  int nCap = (nE < POOL) ? nE : POOL;
  const unsigned short* XLu = (const unsigned short*)XLh;

  // ---- Phase S: edge-per-lane gather + score ----
  for (int slot = t; slot < nCap; slot += 256) {
    int sp = ssrc[bbeg + slot];
    int s = sp >> 5;
    int g = sp & (NPB - 1);
    float v[C];
    if constexpr (C == 16) {
      const uint4* gp = (const uint4*)(XLu + (size_t)s * 16);
      uint4 a = gp[0], b = gp[1];
      *(uint4*)&vpool[slot * 16] = a;
      *(uint4*)&vpool[slot * 16 + 8] = b;
      unsigned arr[8] = {a.x, a.y, a.z, a.w, b.x, b.y, b.z, b.w};
#pragma unroll
      for (int i = 0; i < 8; i++) {
        v[2 * i] = __uint_as_float(arr[i] << 16);
        v[2 * i + 1] = __uint_as_float(arr[i] & 0xffff0000u);
      }
    } else {
      const uint4* gp = (const uint4*)(XLu + (size_t)s * 8);
      uint4 a = gp[0];
      *(uint4*)&vpool[slot * 8] = a;
      unsigned arr[4] = {a.x, a.y, a.z, a.w};
#pragma unroll
      for (int i = 0; i < 4; i++) {
        v[2 * i] = __uint_as_float(arr[i] << 16);
        v[2 * i + 1] = __uint_as_float(arr[i] & 0xffff0000u);
      }
    }
    float xr[C];
    const float4* xp = (const float4*)&xrl[g * C];
#pragma unroll
    for (int q = 0; q < C / 4; q++) {
      float4 f = xp[q];
      xr[4 * q] = f.x;
      xr[4 * q + 1] = f.y;
      xr[4 * q + 2] = f.z;
      xr[4 * q + 3] = f.w;
    }
    float p0 = 0.f, p1 = 0.f, p2 = 0.f, p3 = 0.f;
#pragma unroll
    for (int cc = 0; cc < C; cc += 4) {
      float u0 = v[cc] + xr[cc];
      float u1 = v[cc + 1] + xr[cc + 1];
      float u2 = v[cc + 2] + xr[cc + 2];
      float u3 = v[cc + 3] + xr[cc + 3];
      p0 = fmaf(fmaxf(u0, 0.2f * u0), attr[cc], p0);
      p1 = fmaf(fmaxf(u1, 0.2f * u1), attr[cc + 1], p1);
      p2 = fmaf(fmaxf(u2, 0.2f * u2), attr[cc + 2], p2);
      p3 = fmaf(fmaxf(u3, 0.2f * u3), attr[cc + 3], p3);
    }
    ppool[slot] = __expf((p0 + p1) + (p2 + p3));
  }
  __syncthreads();

  int g = t / C;
  int c = t % C;
  int base = nb[g] - bbeg;
  int deg = nb[g + 1] - nb[g];
  int capd = POOL - base;
  capd = capd < 0 ? 0 : (capd > deg ? deg : capd);

  // ---- Phase D: S0 per node ----
  float invS0;
  {
    float s0 = 0.f;
    for (int j = c; j < capd; j += C) s0 += ppool[base + j];
    for (int j = capd + c; j < deg; j += C) {  // overflow fallback (rare)
      int s = ssrc[bbeg + base + j] >> 5;
      float sc = 0.f;
#pragma unroll
      for (int cc = 0; cc < C; cc++) {
        float v = __bfloat162float(XLh[(size_t)s * C + cc]);
        float u = v + xrl[g * C + cc];
        sc = fmaf(fmaxf(u, 0.2f * u), attr[cc], sc);
      }
      s0 += __expf(sc);
    }
#pragma unroll
    for (int m = 1; m < C; m <<= 1) s0 += __shfl_xor(s0, m, C);
    invS0 = (deg > 0) ? 1.0f / s0 : 0.f;
  }
  float a = invS0 * tval;

  // ---- Phase 2: q = v*p*a; w = exp(q); S1 += w; S2 += w*q ----
  float S1 = 0.f, S2 = 0.f, S1b = 0.f, S2b = 0.f;
  int jj = 0;
  for (; jj + 2 <= capd; jj += 2) {
    int sl0 = base + jj;
    float v0 = __uint_as_float(((unsigned)vpool[sl0 * C + c]) << 16);
    float q0 = v0 * ppool[sl0] * a;
    float v1 = __uint_as_float(((unsigned)vpool[(sl0 + 1) * C + c]) << 16);
    float q1 = v1 * ppool[sl0 + 1] * a;
    float w0 = __expf(q0);
    float w1 = __expf(q1);
    S1 += w0;
    S2 = fmaf(w0, q0, S2);
    S1b += w1;
    S2b = fmaf(w1, q1, S2b);
  }
  for (; jj < capd; jj++) {
    int sl = base + jj;
    float v = __uint_as_float(((unsigned)vpool[sl * C + c]) << 16);
    float q = v * ppool[sl] * a;
    float w = __expf(q);
    S1 += w;
    S2 = fmaf(w, q, S2);
  }
  for (; jj < deg; jj++) {  // overflow fallback (rare)
    int s = ssrc[bbeg + base + jj] >> 5;
    float sc = 0.f, vc = 0.f;
#pragma unroll
    for (int cc = 0; cc < C; cc++) {
      float v = __bfloat162float(XLh[(size_t)s * C + cc]);
      if (cc == c) vc = v;
      float u = v + xrl[g * C + cc];
      sc = fmaf(fmaxf(u, 0.2f * u), attr[cc], sc);
    }
    float p = __expf(sc);
    float q = vc * p * a;
    float w = __expf(q);
    S1 += w;
    S2 = fmaf(w, q, S2);
  }
  S1 += S1b;
  S2 += S2b;

  int node = node0 + g;
  bool valid = node < N;
  float hval = 0.f;
  if (valid) {
    float td = (tval != 0.f) ? tval : 1.f;
    float gat = (deg > 0) ? (S2 / (S1 * td)) : 0.f;
    hval = fmaxf(gat + bias[c] + SK[(size_t)node * C + c], 0.f);
  }
  if constexpr (FUSEG2) {
    __syncthreads();  // vpool dead; hsh aliases it
    hsh[g * C + c] = hval;
    __syncthreads();
    if (t < NPB * 8) {
      int g2 = t >> 3, c2 = t & 7;
      int nd = node0 + g2;
      if (nd < N) {
        float a0 = 0.f, a1 = 0.f, a2 = 0.f;
#pragma unroll
        for (int k = 0; k < 16; k++) {
          float hv = hsh[g2 * 16 + k];
          a0 = fmaf(hv, wfuse[k * 8 + c2], a0);
          a1 = fmaf(hv, wfuse[128 + k * 8 + c2], a1);
          a2 = fmaf(hv, wfuse[256 + k * 8 + c2], a2);
        }
        ((unsigned short*)XL2h)[(size_t)nd * 8 + c2] = f2bf(a0);
        XR2[(size_t)nd * 8 + c2] = a1;
        SK2[(size_t)nd * 8 + c2] = a2 + wfuse[384 + c2];
      }
    }
  } else if constexpr (HEAD) {
    __syncthreads();  // vpool dead; hsh aliases it
    hsh[g * C + c] = hval;
    __syncthreads();
    if (t < NPB) {
      int nd = node0 + t;
      if (nd < N) {
        float h[8];
#pragma unroll
        for (int k = 0; k < 8; k++) h[k] = hsh[t * 8 + k];
        float s4 = 0.f;
#pragma unroll
        for (int cc = 0; cc < 8; cc++) {
          float z = P1[cc];  // b3
#pragma unroll
          for (int k = 0; k < 8; k++) z = fmaf(h[k], P0[k * 8 + cc], z);  // W3
          z = fmaxf(z, 0.f);
          s4 = fmaf(z, P2[cc], s4);  // W4
        }
        s4 = fmaxf(s4 + P3[0], 0.f);                    // b4
        float s5 = fmaxf(fmaf(s4, P4[0], P5[0]), 0.f);  // W5,b5
        float zo = fmaf(s5, P6[0], P7[0]);              // Wout,bout
        float ls;
        if (zo >= 0.f)
          ls = -log1pf(expf(-zo));
        else
          ls = zo - log1pf(expf(zo));
        out[nd] = ls;
      }
    }
  } else {
    if (valid) H[(size_t)node * C + c] = hval;
  }
}

extern "C" void kernel_launch(void* const* d_in, const int* in_sizes, int n_in,
                              void* d_out, int out_size, void* d_ws, size_t ws_size,
                              hipStream_t stream) {
  const float* x = (const float*)d_in[0];
  const int* ei = (const int*)d_in[1];
  const float* Wl1 = (const float*)d_in[3];
  const float* Wr1 = (const float*)d_in[4];
  const float* att1 = (const float*)d_in[5];
  const float* b1 = (const float*)d_in[6];
  const float* Wlin1 = (const float*)d_in[7];
  const float* blin1 = (const float*)d_in[8];
  const float* Wl2 = (const float*)d_in[9];
  const float* Wr2 = (const float*)d_in[10];
  const float* att2 = (const float*)d_in[11];
  const float* b2 = (const float*)d_in[12];
  const float* Wlin2 = (const float*)d_in[13];
  const float* blin2 = (const float*)d_in[14];
  const float* t = (const float*)d_in[15];
  const float* W3 = (const float*)d_in[16];
  const float* b3 = (const float*)d_in[17];
  const float* W4 = (const float*)d_in[18];
  const float* b4 = (const float*)d_in[19];
  const float* W5 = (const float*)d_in[20];
  const float* b5 = (const float*)d_in[21];
  const float* Wout = (const float*)d_in[22];
  const float* bout = (const float*)d_in[23];
  float* out = (float*)d_out;

  int N = in_sizes[0] / F_IN;
  int E = in_sizes[1] / 2;
  const int* src = ei;
  const int* dst = ei + E;
  int NB = (N + LOCAL - 1) >> LBITS;  // 391 for N=100000

  char* ws = (char*)d_ws;
  size_t off = 0;
  auto alloc = [&](size_t bytes) -> void* {
    void* p = ws + off;
    off = (off + bytes + 255) & ~(size_t)255;
    return p;
  };
  int* bcount = (int*)alloc((size_t)NB * 4);
  int* bbase = (int*)alloc((size_t)(NB + 1) * 4);
  int* bcursor = (int*)alloc((size_t)NB * 4);
  int* packed = (int*)alloc((size_t)E * 4);
  int* row_ptr = (int*)alloc((size_t)(N + 1) * 4);
  int* ssrc = (int*)alloc((size_t)E * 4);
  __hip_bfloat16* XL1 = (__hip_bfloat16*)alloc((size_t)N * C1 * 2);
  float* XR1 = (float*)alloc((size_t)N * C1 * 4);
  float* SK1 = (float*)alloc((size_t)N * C1 * 4);
  __hip_bfloat16* XL2 = (__hip_bfloat16*)alloc((size_t)N * C2 * 2);
  float* XR2 = (float*)alloc((size_t)N * C2 * 4);
  float* SK2 = (float*)alloc((size_t)N * C2 * 4);

  int nblkA = (E + EPB - 1) / EPB;
  int nodeBlk = (N + 255) / 256;  // 391

  hipMemsetAsync(bcount, 0, (size_t)NB * 4, stream);
  hipLaunchKernelGGL(hist_gemm, dim3(HISTBLK + nodeBlk * 3), dim3(256), 0, stream, dst, bcount, E,
                     NB, x, Wl1, Wr1, Wlin1, blin1, XL1, XR1, SK1, N);
  hipLaunchKernelGGL(bucket_scan, dim3(1), dim3(NB_MAX), 0, stream, bcount, bbase, bcursor, NB);
  hipLaunchKernelGGL(phaseA_lds, dim3(nblkA), dim3(256), 0, stream, src, dst, bcursor, packed, E,
                     NB);
  hipLaunchKernelGGL(phaseB_sort, dim3(NB), dim3(LOCAL), 0, stream, packed, bbase, row_ptr, ssrc, N,
                     E);
  hipLaunchKernelGGL((gat_layer<16, 576, false, true>), dim3((N + 15) / 16), dim3(256), 0, stream,
                     XL1, XR1, SK1, att1, b1, t, row_ptr, ssrc, nullptr, N, Wl2, Wr2, Wlin2, blin2,
                     nullptr, nullptr, nullptr, nullptr, XL2, XR2, SK2, nullptr);
  hipLaunchKernelGGL((gat_layer<8, 1216, true, false>), dim3((N + 31) / 32), dim3(256), 0, stream,
                     XL2, XR2, SK2, att2, b2, t, row_ptr, ssrc, nullptr, N, W3, b3, W4, b4, W5, b5,
                     Wout, bout, nullptr, nullptr, nullptr, out);
}